// Round 1
// baseline (384.364 us; speedup 1.0000x reference)
//
#include <hip/hip_runtime.h>
#include <hip/hip_fp8.h>

#define EMB 1024
#define HID 4096
#define NB 2
#define TT 4096
#define MROWS (NB*TT)   // 8192
#define N1 (2*HID)      // 8192
#define CHUNK 128       // = column-sum chunk rows
#define NCH 32          // chunks per batch (TT/CHUNK)

typedef short short8 __attribute__((ext_vector_type(8)));
typedef float v4f   __attribute__((ext_vector_type(4)));

__device__ __forceinline__ unsigned short f2bf(float f) {
  unsigned int u = __float_as_uint(f);
  u += 0x7FFFu + ((u >> 16) & 1u);
  return (unsigned short)(u >> 16);
}
__device__ __forceinline__ float bf2f(unsigned short s) {
  return __uint_as_float(((unsigned int)s) << 16);
}
__device__ __forceinline__ float h2f(unsigned short u) {
  return (float)(*(const _Float16*)&u);
}
__device__ __forceinline__ unsigned char f2e4m3(float f) {
  __hip_fp8_e4m3 q(f);
  return *(unsigned char*)&q;
}
__device__ __forceinline__ float e4m32f(unsigned char c) {
  __hip_fp8_e4m3 q = *(__hip_fp8_e4m3*)&c;
  return (float)q;
}
__device__ __forceinline__ void g2l16(const void* g, void* l) {
  __builtin_amdgcn_global_load_lds(
      (const __attribute__((address_space(1))) void*)g,
      (__attribute__((address_space(3))) void*)l, 16, 0, 0);
}

__device__ __forceinline__ float block_reduce_sum(float v, float* sbuf) {
  #pragma unroll
  for (int off = 32; off; off >>= 1) v += __shfl_down(v, off, 64);
  int lane = threadIdx.x & 63, w = threadIdx.x >> 6;
  if (lane == 0) sbuf[w] = v;
  __syncthreads();
  return sbuf[0] + sbuf[1] + sbuf[2] + sbuf[3];
}

// ---------- merged weight convert: W1|W2 -> bf16, W3 -> fp8 x64 ----------
__global__ __launch_bounds__(256) void conv_all(const float* __restrict__ W1,
                                                const float* __restrict__ W2,
                                                const float* __restrict__ W3,
                                                unsigned short* __restrict__ o12,
                                                unsigned char* __restrict__ o3) {
  size_t i = ((size_t)blockIdx.x*256 + threadIdx.x)*4;
  if (i < 2ull*HID*EMB) {
    const float* s = (i < (size_t)HID*EMB) ? (W1 + i) : (W2 + (i - (size_t)HID*EMB));
    float4 v = *(const float4*)s;
    ushort4 u; u.x=f2bf(v.x); u.y=f2bf(v.y); u.z=f2bf(v.z); u.w=f2bf(v.w);
    *(ushort4*)(o12 + i) = u;
  } else {
    size_t off = i - 2ull*HID*EMB;
    float4 v = *(const float4*)(W3 + off);
    uchar4 u; u.x=f2e4m3(v.x*64.f); u.y=f2e4m3(v.y*64.f);
             u.z=f2e4m3(v.z*64.f); u.w=f2e4m3(v.w*64.f);
    *(uchar4*)(o3 + off) = u;
  }
}

// ---------- rmsnorm (fp32 in, bf16 out), row = EMB ----------
__global__ __launch_bounds__(256) void rmsnorm_x(const float* __restrict__ x,
                                                 unsigned short* __restrict__ r) {
  __shared__ float sbuf[4];
  int row = blockIdx.x;
  float4 v = *(const float4*)(x + (size_t)row*EMB + threadIdx.x*4);
  float ss = v.x*v.x + v.y*v.y + v.z*v.z + v.w*v.w;
  float tot = block_reduce_sum(ss, sbuf);
  float sc = rsqrtf(tot * (1.0f/EMB) + 1e-6f);
  ushort4 o; o.x=f2bf(v.x*sc); o.y=f2bf(v.y*sc); o.z=f2bf(v.z*sc); o.w=f2bf(v.w*sc);
  *(ushort4*)(r + (size_t)row*EMB + threadIdx.x*4) = o;
}

// ---------- normalize + quantize: y8 = fp8(y * rsqrt(mean(y^2)+eps)) ----------
__global__ __launch_bounds__(256) void normq(const unsigned short* __restrict__ y,
                                             unsigned char* __restrict__ y8) {
  __shared__ float sbuf[4];
  int row = blockIdx.x;
  const unsigned short* p = y + (size_t)row*HID + threadIdx.x*16;
  short8 v0 = *(const short8*)p;
  short8 v1 = *(const short8*)(p+8);
  float f[16]; float ss = 0.f;
  #pragma unroll
  for (int j=0;j<8;++j){ f[j]=bf2f((unsigned short)v0[j]); f[j+8]=bf2f((unsigned short)v1[j]); }
  #pragma unroll
  for (int j=0;j<16;++j) ss += f[j]*f[j];
  float tot = block_reduce_sum(ss, sbuf);
  float sc = rsqrtf(tot*(1.0f/HID) + 1e-6f);
  unsigned int w[4];
  #pragma unroll
  for (int g=0; g<4; ++g) {
    unsigned int a0 = f2e4m3(f[g*4+0]*sc);
    unsigned int a1 = f2e4m3(f[g*4+1]*sc);
    unsigned int a2 = f2e4m3(f[g*4+2]*sc);
    unsigned int a3 = f2e4m3(f[g*4+3]*sc);
    w[g] = a0 | (a1<<8) | (a2<<16) | (a3<<24);
  }
  uint4 o; o.x=w[0]; o.y=w[1]; o.z=w[2]; o.w=w[3];
  *(uint4*)(y8 + (size_t)row*HID + threadIdx.x*16) = o;
}

// ---------- GEMM1: C8 = (fp8 e4m3) exp(A*Bt^T); col-chunk sums -> part ----------
// 256x256 tile, 8 waves (2Mx4N), BK=32, ring-4 LDS (128 KB), counted vmcnt(8)
// pipeline (prefetch distance 2 K-tiles), one raw s_barrier per K-tile,
// setprio around the MFMA cluster. XOR swizzle: slot(m,c) =
// ((m ^ ((m>>2)&1))<<2) | (c ^ (m&3))  -> all 8 bank-groups hit per 16 rows.
// Staging pre-swizzles the GLOBAL source; LDS dest stays linear (g2l16 rule).
// XCD swizzle: xcd = bid&7 owns 4 col-tiles; cols cycle fastest within stripe.
__global__ __launch_bounds__(512, 2)
void gemm_exp(const unsigned short* __restrict__ A,
              const unsigned short* __restrict__ Bt,
              unsigned char* __restrict__ C8,
              float* __restrict__ part,
              int K, int N) {
  __shared__ short lds[4][2][256*32];   // [buf][A|B][slot*8] = 128 KiB
  const int tid  = threadIdx.x;
  const int lane = tid & 63;
  const int wid  = tid >> 6;
  const int wr   = wid >> 2;           // 0..1  (128-row slice = one chunk)
  const int wc   = wid & 3;            // 0..3  (64-col slice)
  const int bid  = blockIdx.x;
  const int s0   = bid >> 3;
  const int colTile = ((bid & 7) << 2) | (s0 & 3);  // 0..31
  const int rowTile = s0 >> 2;                      // 0..31
  const int rowBase = rowTile << 8;
  const int colBase = colTile << 8;
  const int NT = K >> 5;               // K-tiles of 32

  v4f acc[8][4];
  #pragma unroll
  for (int i=0;i<8;++i)
    #pragma unroll
    for (int j=0;j<4;++j) acc[i][j] = (v4f){0.f,0.f,0.f,0.f};

  // stage one K-tile: 4 global_load_lds per thread (2 A + 2 B)
  auto stage = [&](int t) {
    const int buf = t & 3;
    const int k0  = t << 5;
    #pragma unroll
    for (int j = 0; j < 2; ++j) {
      int slot = j*512 + tid;
      int msw  = slot >> 2;
      int m    = msw ^ ((msw >> 2) & 1);
      int c    = (slot & 3) ^ (m & 3);
      g2l16(A + (size_t)(rowBase + m)*K + k0 + c*8, &lds[buf][0][slot*8]);
    }
    #pragma unroll
    for (int j = 0; j < 2; ++j) {
      int slot = j*512 + tid;
      int msw  = slot >> 2;
      int m    = msw ^ ((msw >> 2) & 1);
      int c    = (slot & 3) ^ (m & 3);
      g2l16(Bt + (size_t)(colBase + m)*K + k0 + c*8, &lds[buf][1][slot*8]);
    }
  };

  stage(0);
  if (NT > 1) stage(1);

  const int q   = lane >> 4;
  const int r15 = lane & 15;

  for (int t = 0; t < NT; ++t) {
    if (t + 2 < NT) stage(t + 2);
    // counted waits: own 4 loads for tile t are the oldest outstanding
    if (t + 2 < NT)      asm volatile("s_waitcnt vmcnt(8)" ::: "memory");
    else if (t + 1 < NT) asm volatile("s_waitcnt vmcnt(4)" ::: "memory");
    else                 asm volatile("s_waitcnt vmcnt(0)" ::: "memory");
    __builtin_amdgcn_s_barrier();          // everyone's tile-t loads landed
    __builtin_amdgcn_sched_barrier(0);     // pin ds_reads after the barrier

    const short* lA = &lds[t & 3][0][0];
    const short* lB = &lds[t & 3][1][0];
    short8 aF[4], bF[4], aG[4];
    #pragma unroll
    for (int mt = 0; mt < 4; ++mt) {
      int m = wr*128 + mt*16 + r15;
      int slot = ((m ^ ((m >> 2) & 1)) << 2) | (q ^ (m & 3));
      aF[mt] = *(const short8*)&lA[slot*8];
    }
    #pragma unroll
    for (int nt = 0; nt < 4; ++nt) {
      int n = wc*64 + nt*16 + r15;
      int slot = ((n ^ ((n >> 2) & 1)) << 2) | (q ^ (n & 3));
      bF[nt] = *(const short8*)&lB[slot*8];
    }
    #pragma unroll
    for (int mt = 0; mt < 4; ++mt) {
      int m = wr*128 + (mt+4)*16 + r15;
      int slot = ((m ^ ((m >> 2) & 1)) << 2) | (q ^ (m & 3));
      aG[mt] = *(const short8*)&lA[slot*8];
    }
    __builtin_amdgcn_s_setprio(1);
    #pragma unroll
    for (int mt = 0; mt < 4; ++mt)
      #pragma unroll
      for (int nt = 0; nt < 4; ++nt)
        acc[mt][nt] = __builtin_amdgcn_mfma_f32_16x16x32_bf16(aF[mt], bF[nt], acc[mt][nt], 0, 0, 0);
    #pragma unroll
    for (int mt = 0; mt < 4; ++mt)
      #pragma unroll
      for (int nt = 0; nt < 4; ++nt)
        acc[mt+4][nt] = __builtin_amdgcn_mfma_f32_16x16x32_bf16(aG[mt], bF[nt], acc[mt+4][nt], 0, 0, 0);
    __builtin_amdgcn_s_setprio(0);
  }

  // epilogue: exp -> fp8 store + per-128-row-chunk column sums.
  // wave (wr) owns a full chunk -> only quad-reduce needed, no LDS, no barrier.
  float csum[4] = {0.f, 0.f, 0.f, 0.f};
  #pragma unroll
  for (int mt = 0; mt < 8; ++mt) {
    #pragma unroll
    for (int nt = 0; nt < 4; ++nt) {
      int col = colBase + wc*64 + nt*16 + r15;
      #pragma unroll
      for (int rr = 0; rr < 4; ++rr) {
        int row = rowBase + wr*128 + mt*16 + q*4 + rr;
        float e = __expf(acc[mt][nt][rr]);
        C8[(size_t)row*N + col] = f2e4m3(e);
        csum[nt] += e;
      }
    }
  }
  const int chunk = rowTile*2 + wr;     // 0..63
  #pragma unroll
  for (int nt = 0; nt < 4; ++nt) {
    float v = csum[nt];
    v += __shfl_xor(v, 16, 64);
    v += __shfl_xor(v, 32, 64);
    if (lane < 16)
      part[(size_t)(colBase + wc*64 + nt*16 + lane)*64 + chunk] = v;
  }
}

// ---------- GEMM2 (fp8): Ph[z] = (fp16) yhat8 * (w3*64)^T, split-K ----------
// 128x128 tile, BK=128 fp8, 16+16 KB LDS, XOR-swizzled 16B chunks.
// Grid (row=64, col=8, z=4): id%8 = rowTile%8 -> all col-tiles sharing an
// A-tile land on one XCD; per-XCD A+B working set ~2 MB stays L2-resident.
__global__ __launch_bounds__(256, 2)
void gemm_out(const unsigned char* __restrict__ A8,
              const unsigned char* __restrict__ B8,
              unsigned short* __restrict__ Ph,
              int K, int KCH, int N) {
  __shared__ unsigned char lA8[128*128];
  __shared__ unsigned char lB8[128*128];
  const int tid  = threadIdx.x;
  const int lane = tid & 63;
  const int wm   = (tid >> 6) >> 1, wn = (tid >> 6) & 1;
  const int rowBase = blockIdx.x * 128;
  const int colBase = blockIdx.y * 128;
  const int kStart  = blockIdx.z * KCH;

  v4f acc[4][4];
  #pragma unroll
  for (int i=0;i<4;++i)
    #pragma unroll
    for (int j=0;j<4;++j) acc[i][j] = (v4f){0.f,0.f,0.f,0.f};

  for (int k0 = kStart; k0 < kStart + KCH; k0 += 128) {
    #pragma unroll
    for (int j = 0; j < 4; ++j) {
      int s = j*256 + tid;
      int m = s >> 3;
      int c = (s & 7) ^ (m & 7);
      g2l16(A8 + (size_t)(rowBase + m)*K + k0 + c*16, &lA8[s*16]);
    }
    #pragma unroll
    for (int j = 0; j < 4; ++j) {
      int s = j*256 + tid;
      int m = s >> 3;
      int c = (s & 7) ^ (m & 7);
      g2l16(B8 + (size_t)(colBase + m)*K + k0 + c*16, &lB8[s*16]);
    }
    __syncthreads();
    #pragma unroll
    for (int s2 = 0; s2 < 4; ++s2) {
      const int quad = lane >> 4;
      const int cc = s2*2 + (quad >> 1);   // logical 16B chunk
      const int hh = quad & 1;             // 8B half within chunk
      long aF[4], bF[4];
      #pragma unroll
      for (int mt = 0; mt < 4; ++mt) {
        int ml = wm*64 + mt*16 + (lane & 15);
        aF[mt] = *(const long*)&lA8[ml*128 + ((cc ^ (ml & 7))<<4) + (hh<<3)];
      }
      #pragma unroll
      for (int nt = 0; nt < 4; ++nt) {
        int nl = wn*64 + nt*16 + (lane & 15);
        bF[nt] = *(const long*)&lB8[nl*128 + ((cc ^ (nl & 7))<<4) + (hh<<3)];
      }
      #pragma unroll
      for (int mt = 0; mt < 4; ++mt)
        #pragma unroll
        for (int nt = 0; nt < 4; ++nt)
          acc[mt][nt] = __builtin_amdgcn_mfma_f32_16x16x32_fp8_fp8(aF[mt], bF[nt], acc[mt][nt], 0, 0, 0);
    }
    __syncthreads();
  }

  const int quad = lane >> 4, c15 = lane & 15;
  #pragma unroll
  for (int mt = 0; mt < 4; ++mt) {
    #pragma unroll
    for (int nt = 0; nt < 4; ++nt) {
      int col = colBase + wn*64 + nt*16 + c15;
      #pragma unroll
      for (int r = 0; r < 4; ++r) {
        int row = rowBase + wm*64 + mt*16 + quad*4 + r;
        size_t idx = ((size_t)blockIdx.z*MROWS + row)*N + col;
        _Float16 h = (_Float16)acc[mt][nt][r];
        Ph[idx] = *(unsigned short*)&h;
      }
    }
  }
}

// ---------- exclusive prefix over 32 chunks per (col, batch) ----------
__global__ __launch_bounds__(256) void scan_prefix(float* __restrict__ part) {
  int idx = blockIdx.x*256 + threadIdx.x;   // 0..16383
  int col = idx >> 1, bb = idx & 1;
  float* p = part + (size_t)col*64 + bb*NCH;
  float run = 0.f;
  #pragma unroll
  for (int c = 0; c < NCH; ++c) { float v = p[c]; p[c] = run; run += v; }
}

// ---------- emit y = Sa*Sb/t^2 (bf16) from fp8 exp values ----------
__global__ __launch_bounds__(256) void scan_emit(const unsigned char* __restrict__ ab,
                                                 const float* __restrict__ part,
                                                 unsigned short* __restrict__ y) {
  int h = blockIdx.x*256 + threadIdx.x;     // 0..4095
  int cy = blockIdx.y, bb = blockIdx.z;
  float sa = part[(size_t)h*64 + bb*NCH + cy];
  float sb = part[(size_t)(HID + h)*64 + bb*NCH + cy];
  const unsigned char* pa = ab + ((size_t)(bb*TT + cy*CHUNK))*N1 + h;
  const unsigned char* pb = pa + HID;
  unsigned short* py = y + ((size_t)(bb*TT + cy*CHUNK))*HID + h;
  int t0 = cy*CHUNK;
  #pragma unroll 4
  for (int i = 0; i < CHUNK; ++i) {
    sa += e4m32f(pa[(size_t)i*N1]);
    sb += e4m32f(pb[(size_t)i*N1]);
    float inv = 1.0f / (float)(t0 + i + 1);
    py[(size_t)i*HID] = f2bf(sa*sb*inv*inv);
  }
}

// ---------- out = x + (1/64)*sum_z partial_z (fp16 partials) ----------
__global__ __launch_bounds__(256) void reduce_out(const unsigned short* __restrict__ p,
                                                  const float* __restrict__ x,
                                                  float* __restrict__ o) {
  size_t i = ((size_t)blockIdx.x*256 + threadIdx.x)*4;
  float4 xv = *(const float4*)(x + i);
  float s0 = 0.f, s1 = 0.f, s2 = 0.f, s3 = 0.f;
  #pragma unroll
  for (int z = 0; z < 4; ++z) {
    ushort4 u = *(const ushort4*)(p + (size_t)z*MROWS*EMB + i);
    s0 += h2f(u.x); s1 += h2f(u.y); s2 += h2f(u.z); s3 += h2f(u.w);
  }
  const float inv64 = 1.0f/64.0f;
  float4 ov; ov.x = xv.x + inv64*s0; ov.y = xv.y + inv64*s1;
             ov.z = xv.z + inv64*s2; ov.w = xv.w + inv64*s3;
  *(float4*)(o + i) = ov;
}

extern "C" void kernel_launch(void* const* d_in, const int* in_sizes, int n_in,
                              void* d_out, int out_size, void* d_ws, size_t ws_size,
                              hipStream_t stream) {
  const float* x  = (const float*)d_in[0];
  const float* W1 = (const float*)d_in[1];
  const float* W2 = (const float*)d_in[2];
  const float* W3 = (const float*)d_in[3];
  float* out = (float*)d_out;
  char* ws = (char*)d_ws;

  unsigned short* r_bf   = (unsigned short*)(ws);                 // 16 MiB
  unsigned short* w12_bf = (unsigned short*)(ws + 16777216ull);   // 16 MiB
  unsigned char*  w3_8   = (unsigned char*) (ws + 33554432ull);   // 4 MiB fp8 (x64)
  unsigned char*  ab8    = (unsigned char*) (ws + 37748736ull);   // 64 MiB fp8
  unsigned short* y_bf   = (unsigned short*)(ws + 104857600ull);  // 64 MiB
  unsigned char*  y8     = (unsigned char*) (ws + 171966464ull);  // 32 MiB fp8 (normalized)
  // psum (4 x 16 MiB fp16 GEMM2 partials) reuses dead ab8 (exactly 64 MiB)
  unsigned short* psum   = (unsigned short*)ab8;
  // part (per-chunk column sums) lives in d_out; dead before reduce_out
  float*          part   = (float*)d_out;                         // 2 MB

  conv_all<<<12288, 256, 0, stream>>>(W1, W2, W3, w12_bf, w3_8);
  rmsnorm_x<<<MROWS, 256, 0, stream>>>(x, r_bf);
  gemm_exp<<<1024, 512, 0, stream>>>(r_bf, w12_bf, ab8, part, EMB, N1);
  scan_prefix<<<64, 256, 0, stream>>>(part);
  scan_emit<<<dim3(16,NCH,2), 256, 0, stream>>>(ab8, part, y_bf);
  normq<<<MROWS, 256, 0, stream>>>(y_bf, y8);
  gemm_out<<<dim3(64,8,4), 256, 0, stream>>>(y8, w3_8, psum, HID, 1024, EMB);
  reduce_out<<<8192, 256, 0, stream>>>(psum, x, out);
}

// Round 2
// 382.752 us; speedup vs baseline: 1.0042x; 1.0042x over previous
//
#include <hip/hip_runtime.h>
#include <hip/hip_fp8.h>

#define EMB 1024
#define HID 4096
#define NB 2
#define TT 4096
#define MROWS (NB*TT)   // 8192
#define N1 (2*HID)      // 8192
#define CHUNK 128       // = column-sum chunk rows
#define NCH 32          // chunks per batch (TT/CHUNK)

typedef short short8 __attribute__((ext_vector_type(8)));
typedef float v4f   __attribute__((ext_vector_type(4)));

__device__ __forceinline__ unsigned short f2bf(float f) {
  unsigned int u = __float_as_uint(f);
  u += 0x7FFFu + ((u >> 16) & 1u);
  return (unsigned short)(u >> 16);
}
__device__ __forceinline__ float bf2f(unsigned short s) {
  return __uint_as_float(((unsigned int)s) << 16);
}
__device__ __forceinline__ float h2f(unsigned short u) {
  return (float)(*(const _Float16*)&u);
}
__device__ __forceinline__ unsigned char f2e4m3(float f) {
  __hip_fp8_e4m3 q(f);
  return *(unsigned char*)&q;
}
__device__ __forceinline__ float e4m32f(unsigned char c) {
  __hip_fp8_e4m3 q = *(__hip_fp8_e4m3*)&c;
  return (float)q;
}
__device__ __forceinline__ void g2l16(const void* g, void* l) {
  __builtin_amdgcn_global_load_lds(
      (const __attribute__((address_space(1))) void*)g,
      (__attribute__((address_space(3))) void*)l, 16, 0, 0);
}

__device__ __forceinline__ float block_reduce_sum(float v, float* sbuf) {
  #pragma unroll
  for (int off = 32; off; off >>= 1) v += __shfl_down(v, off, 64);
  int lane = threadIdx.x & 63, w = threadIdx.x >> 6;
  if (lane == 0) sbuf[w] = v;
  __syncthreads();
  return sbuf[0] + sbuf[1] + sbuf[2] + sbuf[3];
}

// ---------- merged weight convert: W1|W2 -> bf16, W3 -> fp8 x64 ----------
__global__ __launch_bounds__(256) void conv_all(const float* __restrict__ W1,
                                                const float* __restrict__ W2,
                                                const float* __restrict__ W3,
                                                unsigned short* __restrict__ o12,
                                                unsigned char* __restrict__ o3) {
  size_t i = ((size_t)blockIdx.x*256 + threadIdx.x)*4;
  if (i < 2ull*HID*EMB) {
    const float* s = (i < (size_t)HID*EMB) ? (W1 + i) : (W2 + (i - (size_t)HID*EMB));
    float4 v = *(const float4*)s;
    ushort4 u; u.x=f2bf(v.x); u.y=f2bf(v.y); u.z=f2bf(v.z); u.w=f2bf(v.w);
    *(ushort4*)(o12 + i) = u;
  } else {
    size_t off = i - 2ull*HID*EMB;
    float4 v = *(const float4*)(W3 + off);
    uchar4 u; u.x=f2e4m3(v.x*64.f); u.y=f2e4m3(v.y*64.f);
             u.z=f2e4m3(v.z*64.f); u.w=f2e4m3(v.w*64.f);
    *(uchar4*)(o3 + off) = u;
  }
}

// ---------- rmsnorm (fp32 in, bf16 out), row = EMB ----------
__global__ __launch_bounds__(256) void rmsnorm_x(const float* __restrict__ x,
                                                 unsigned short* __restrict__ r) {
  __shared__ float sbuf[4];
  int row = blockIdx.x;
  float4 v = *(const float4*)(x + (size_t)row*EMB + threadIdx.x*4);
  float ss = v.x*v.x + v.y*v.y + v.z*v.z + v.w*v.w;
  float tot = block_reduce_sum(ss, sbuf);
  float sc = rsqrtf(tot * (1.0f/EMB) + 1e-6f);
  ushort4 o; o.x=f2bf(v.x*sc); o.y=f2bf(v.y*sc); o.z=f2bf(v.z*sc); o.w=f2bf(v.w*sc);
  *(ushort4*)(r + (size_t)row*EMB + threadIdx.x*4) = o;
}

// ---------- normalize + quantize: y8 = fp8(y * rsqrt(mean(y^2)+eps)) ----------
__global__ __launch_bounds__(256) void normq(const unsigned short* __restrict__ y,
                                             unsigned char* __restrict__ y8) {
  __shared__ float sbuf[4];
  int row = blockIdx.x;
  const unsigned short* p = y + (size_t)row*HID + threadIdx.x*16;
  short8 v0 = *(const short8*)p;
  short8 v1 = *(const short8*)(p+8);
  float f[16]; float ss = 0.f;
  #pragma unroll
  for (int j=0;j<8;++j){ f[j]=bf2f((unsigned short)v0[j]); f[j+8]=bf2f((unsigned short)v1[j]); }
  #pragma unroll
  for (int j=0;j<16;++j) ss += f[j]*f[j];
  float tot = block_reduce_sum(ss, sbuf);
  float sc = rsqrtf(tot*(1.0f/HID) + 1e-6f);
  unsigned int w[4];
  #pragma unroll
  for (int g=0; g<4; ++g) {
    unsigned int a0 = f2e4m3(f[g*4+0]*sc);
    unsigned int a1 = f2e4m3(f[g*4+1]*sc);
    unsigned int a2 = f2e4m3(f[g*4+2]*sc);
    unsigned int a3 = f2e4m3(f[g*4+3]*sc);
    w[g] = a0 | (a1<<8) | (a2<<16) | (a3<<24);
  }
  uint4 o; o.x=w[0]; o.y=w[1]; o.z=w[2]; o.w=w[3];
  *(uint4*)(y8 + (size_t)row*HID + threadIdx.x*16) = o;
}

// ---------- GEMM1: C8 = (fp8 e4m3) exp(A*Bt^T); col-chunk sums -> part ----------
// m201-style 8-phase 256x256 schedule, BK=64 staged as two K-halves of 32.
// 8 waves (2M x 4N); per phase: {ds_read 4-8 x b128 | stage 1 K-half (2 g2l16)}
// -> s_barrier -> lgkmcnt(0) -> setprio(1) -> 16 MFMA -> setprio(0) -> barrier.
// Counted waits only: vmcnt(4) at end-P0, vmcnt(6) at end-P3 (never 0 in loop).
// LDS 2 dbuf x 2 khalf x 256 rows x 32k bf16 (A+B) = 128 KiB.
// Swizzle: slot = m*4 + (c ^ ((m>>1)&3)) -> lanes 0..7 hit all 8 bank-groups.
// XCD swizzle: xcd = bid&7 owns 4 col-tiles; cols cycle fastest within stripe.
__global__ __launch_bounds__(512, 2)
void gemm_exp(const unsigned short* __restrict__ A,
              const unsigned short* __restrict__ Bt,
              unsigned char* __restrict__ C8,
              float* __restrict__ part,
              int K, int N) {
  __shared__ short sA[2][2][8192];   // [buf][khalf][slot*8] = 64 KiB
  __shared__ short sB[2][2][8192];   // 64 KiB
  const int tid  = threadIdx.x;
  const int lane = tid & 63;
  const int wid  = tid >> 6;
  const int wr   = wid >> 2;           // 0..1  (128-row slice = one chunk)
  const int wc   = wid & 3;            // 0..3  (64-col slice)
  const int bid  = blockIdx.x;
  const int s0   = bid >> 3;
  const int colTile = ((bid & 7) << 2) | (s0 & 3);  // 0..31
  const int rowTile = s0 >> 2;                      // 0..31
  const int rowBase = rowTile << 8;
  const int colBase = colTile << 8;
  const int NT = K >> 6;               // K-tiles of 64
  const int q   = lane >> 4;           // k-quad within a 32-k half
  const int r15 = lane & 15;

  v4f acc[8][4];
  #pragma unroll
  for (int i=0;i<8;++i)
    #pragma unroll
    for (int j=0;j<4;++j) acc[i][j] = (v4f){0.f,0.f,0.f,0.f};

  // stage one K-half (256 rows x 32 k = 16 KiB): 2 g2l16 per thread.
  // dest slots linear per wave; global source pre-swizzled to match reads.
  auto stageA = [&](int T, int kh) {
    int Tw = (T >= NT) ? T - NT : T;          // wrapped (tail stages are dead)
    int kb = (Tw << 6) + (kh << 5);
    short* dst = &sA[T & 1][kh][0];
    #pragma unroll
    for (int j = 0; j < 2; ++j) {
      int s = j*512 + tid;
      int m = s >> 2;
      int c = (s & 3) ^ ((m >> 1) & 3);
      g2l16(A + (size_t)(rowBase + m)*K + kb + c*8, dst + s*8);
    }
  };
  auto stageB = [&](int T, int kh) {
    int Tw = (T >= NT) ? T - NT : T;
    int kb = (Tw << 6) + (kh << 5);
    short* dst = &sB[T & 1][kh][0];
    #pragma unroll
    for (int j = 0; j < 2; ++j) {
      int s = j*512 + tid;
      int m = s >> 2;
      int c = (s & 3) ^ ((m >> 1) & 3);
      g2l16(Bt + (size_t)(colBase + m)*K + kb + c*8, dst + s*8);
    }
  };
  auto rdA = [&](int mt, int kh, int buf) -> short8 {
    int m = wr*128 + mt*16 + r15;
    int slot = m*4 + (q ^ ((m >> 1) & 3));
    return *(const short8*)&sA[buf][kh][slot*8];
  };
  auto rdB = [&](int nt, int kh, int buf) -> short8 {
    int n = wc*64 + nt*16 + r15;
    int slot = n*4 + (q ^ ((n >> 1) & 3));
    return *(const short8*)&sB[buf][kh][slot*8];
  };

  // prologue: A0(0) B0(0) A1(0) B1(0) A0(1); wait oldest 2 halves (vmcnt 6)
  stageA(0, 0); stageB(0, 0); stageA(0, 1); stageB(0, 1); stageA(1, 0);
  asm volatile("s_waitcnt vmcnt(6)" ::: "memory");
  __builtin_amdgcn_s_barrier();

  for (int t = 0; t < NT; ++t) {
    const int buf = t & 1;
    short8 aFr[4], bK0[4], bK1[4];

    // ---- P0: reads A-kh0(mt0-3) + B-kh0; stages B-kh0(t+1) ----
    #pragma unroll
    for (int mt = 0; mt < 4; ++mt) aFr[mt] = rdA(mt, 0, buf);
    #pragma unroll
    for (int nt = 0; nt < 4; ++nt) bK0[nt] = rdB(nt, 0, buf);
    stageB(t + 1, 0);
    __builtin_amdgcn_sched_barrier(0);
    __builtin_amdgcn_s_barrier();
    asm volatile("s_waitcnt lgkmcnt(0)" ::: "memory");
    __builtin_amdgcn_sched_barrier(0);
    __builtin_amdgcn_s_setprio(1);
    #pragma unroll
    for (int mt = 0; mt < 4; ++mt)
      #pragma unroll
      for (int nt = 0; nt < 4; ++nt)
        acc[mt][nt] = __builtin_amdgcn_mfma_f32_16x16x32_bf16(aFr[mt], bK0[nt], acc[mt][nt], 0, 0, 0);
    __builtin_amdgcn_s_setprio(0);
    asm volatile("s_waitcnt vmcnt(4)" ::: "memory");   // A-kh1(t), B-kh1(t) landed
    __builtin_amdgcn_s_barrier();

    // ---- P1: reads A-kh1(mt0-3) + B-kh1; stages A-kh1(t+1) ----
    #pragma unroll
    for (int mt = 0; mt < 4; ++mt) aFr[mt] = rdA(mt, 1, buf);
    #pragma unroll
    for (int nt = 0; nt < 4; ++nt) bK1[nt] = rdB(nt, 1, buf);
    stageA(t + 1, 1);
    __builtin_amdgcn_sched_barrier(0);
    __builtin_amdgcn_s_barrier();
    asm volatile("s_waitcnt lgkmcnt(0)" ::: "memory");
    __builtin_amdgcn_sched_barrier(0);
    __builtin_amdgcn_s_setprio(1);
    #pragma unroll
    for (int mt = 0; mt < 4; ++mt)
      #pragma unroll
      for (int nt = 0; nt < 4; ++nt)
        acc[mt][nt] = __builtin_amdgcn_mfma_f32_16x16x32_bf16(aFr[mt], bK1[nt], acc[mt][nt], 0, 0, 0);
    __builtin_amdgcn_s_setprio(0);
    __builtin_amdgcn_s_barrier();

    // ---- P2: reads A-kh0(mt4-7); reuses bK0; stages B-kh1(t+1) ----
    #pragma unroll
    for (int mt = 0; mt < 4; ++mt) aFr[mt] = rdA(mt + 4, 0, buf);
    stageB(t + 1, 1);
    __builtin_amdgcn_sched_barrier(0);
    __builtin_amdgcn_s_barrier();
    asm volatile("s_waitcnt lgkmcnt(0)" ::: "memory");
    __builtin_amdgcn_sched_barrier(0);
    __builtin_amdgcn_s_setprio(1);
    #pragma unroll
    for (int mt = 0; mt < 4; ++mt)
      #pragma unroll
      for (int nt = 0; nt < 4; ++nt)
        acc[mt+4][nt] = __builtin_amdgcn_mfma_f32_16x16x32_bf16(aFr[mt], bK0[nt], acc[mt+4][nt], 0, 0, 0);
    __builtin_amdgcn_s_setprio(0);
    __builtin_amdgcn_s_barrier();

    // ---- P3: reads A-kh1(mt4-7); reuses bK1; stages A-kh0(t+2) ----
    #pragma unroll
    for (int mt = 0; mt < 4; ++mt) aFr[mt] = rdA(mt + 4, 1, buf);
    stageA(t + 2, 0);
    __builtin_amdgcn_sched_barrier(0);
    __builtin_amdgcn_s_barrier();
    asm volatile("s_waitcnt lgkmcnt(0)" ::: "memory");
    __builtin_amdgcn_sched_barrier(0);
    __builtin_amdgcn_s_setprio(1);
    #pragma unroll
    for (int mt = 0; mt < 4; ++mt)
      #pragma unroll
      for (int nt = 0; nt < 4; ++nt)
        acc[mt+4][nt] = __builtin_amdgcn_mfma_f32_16x16x32_bf16(aFr[mt], bK1[nt], acc[mt+4][nt], 0, 0, 0);
    __builtin_amdgcn_s_setprio(0);
    asm volatile("s_waitcnt vmcnt(6)" ::: "memory");   // A-kh0(t+1), B-kh0(t+1) landed
    __builtin_amdgcn_s_barrier();
  }

  // epilogue: exp -> fp8 store + per-128-row-chunk column sums.
  // wave (wr) owns a full chunk -> only quad-reduce needed, no LDS, no barrier.
  float csum[4] = {0.f, 0.f, 0.f, 0.f};
  #pragma unroll
  for (int mt = 0; mt < 8; ++mt) {
    #pragma unroll
    for (int nt = 0; nt < 4; ++nt) {
      int col = colBase + wc*64 + nt*16 + r15;
      #pragma unroll
      for (int rr = 0; rr < 4; ++rr) {
        int row = rowBase + wr*128 + mt*16 + q*4 + rr;
        float e = __expf(acc[mt][nt][rr]);
        C8[(size_t)row*N + col] = f2e4m3(e);
        csum[nt] += e;
      }
    }
  }
  const int chunk = rowTile*2 + wr;     // 0..63
  #pragma unroll
  for (int nt = 0; nt < 4; ++nt) {
    float v = csum[nt];
    v += __shfl_xor(v, 16, 64);
    v += __shfl_xor(v, 32, 64);
    if (lane < 16)
      part[(size_t)(colBase + wc*64 + nt*16 + lane)*64 + chunk] = v;
  }
}

// ---------- GEMM2 (fp8): Ph[z] = (fp16) yhat8 * (w3*64)^T, split-K ----------
// 128x128 tile, BK=128 fp8, 16+16 KB LDS, XOR-swizzled 16B chunks.
// Grid (row=64, col=8, z=4): id%8 = rowTile%8 -> all col-tiles sharing an
// A-tile land on one XCD; per-XCD A+B working set ~2 MB stays L2-resident.
__global__ __launch_bounds__(256, 2)
void gemm_out(const unsigned char* __restrict__ A8,
              const unsigned char* __restrict__ B8,
              unsigned short* __restrict__ Ph,
              int K, int KCH, int N) {
  __shared__ unsigned char lA8[128*128];
  __shared__ unsigned char lB8[128*128];
  const int tid  = threadIdx.x;
  const int lane = tid & 63;
  const int wm   = (tid >> 6) >> 1, wn = (tid >> 6) & 1;
  const int rowBase = blockIdx.x * 128;
  const int colBase = blockIdx.y * 128;
  const int kStart  = blockIdx.z * KCH;

  v4f acc[4][4];
  #pragma unroll
  for (int i=0;i<4;++i)
    #pragma unroll
    for (int j=0;j<4;++j) acc[i][j] = (v4f){0.f,0.f,0.f,0.f};

  for (int k0 = kStart; k0 < kStart + KCH; k0 += 128) {
    #pragma unroll
    for (int j = 0; j < 4; ++j) {
      int s = j*256 + tid;
      int m = s >> 3;
      int c = (s & 7) ^ (m & 7);
      g2l16(A8 + (size_t)(rowBase + m)*K + k0 + c*16, &lA8[s*16]);
    }
    #pragma unroll
    for (int j = 0; j < 4; ++j) {
      int s = j*256 + tid;
      int m = s >> 3;
      int c = (s & 7) ^ (m & 7);
      g2l16(B8 + (size_t)(colBase + m)*K + k0 + c*16, &lB8[s*16]);
    }
    __syncthreads();
    #pragma unroll
    for (int s2 = 0; s2 < 4; ++s2) {
      const int quad = lane >> 4;
      const int cc = s2*2 + (quad >> 1);   // logical 16B chunk
      const int hh = quad & 1;             // 8B half within chunk
      long aF[4], bF[4];
      #pragma unroll
      for (int mt = 0; mt < 4; ++mt) {
        int ml = wm*64 + mt*16 + (lane & 15);
        aF[mt] = *(const long*)&lA8[ml*128 + ((cc ^ (ml & 7))<<4) + (hh<<3)];
      }
      #pragma unroll
      for (int nt = 0; nt < 4; ++nt) {
        int nl = wn*64 + nt*16 + (lane & 15);
        bF[nt] = *(const long*)&lB8[nl*128 + ((cc ^ (nl & 7))<<4) + (hh<<3)];
      }
      #pragma unroll
      for (int mt = 0; mt < 4; ++mt)
        #pragma unroll
        for (int nt = 0; nt < 4; ++nt)
          acc[mt][nt] = __builtin_amdgcn_mfma_f32_16x16x32_fp8_fp8(aF[mt], bF[nt], acc[mt][nt], 0, 0, 0);
    }
    __syncthreads();
  }

  const int quad = lane >> 4, c15 = lane & 15;
  #pragma unroll
  for (int mt = 0; mt < 4; ++mt) {
    #pragma unroll
    for (int nt = 0; nt < 4; ++nt) {
      int col = colBase + wn*64 + nt*16 + c15;
      #pragma unroll
      for (int r = 0; r < 4; ++r) {
        int row = rowBase + wm*64 + mt*16 + quad*4 + r;
        size_t idx = ((size_t)blockIdx.z*MROWS + row)*N + col;
        _Float16 h = (_Float16)acc[mt][nt][r];
        Ph[idx] = *(unsigned short*)&h;
      }
    }
  }
}

// ---------- exclusive prefix over 32 chunks per (col, batch) ----------
__global__ __launch_bounds__(256) void scan_prefix(float* __restrict__ part) {
  int idx = blockIdx.x*256 + threadIdx.x;   // 0..16383
  int col = idx >> 1, bb = idx & 1;
  float* p = part + (size_t)col*64 + bb*NCH;
  float run = 0.f;
  #pragma unroll
  for (int c = 0; c < NCH; ++c) { float v = p[c]; p[c] = run; run += v; }
}

// ---------- emit y = Sa*Sb/t^2 (bf16) from fp8 exp values ----------
__global__ __launch_bounds__(256) void scan_emit(const unsigned char* __restrict__ ab,
                                                 const float* __restrict__ part,
                                                 unsigned short* __restrict__ y) {
  int h = blockIdx.x*256 + threadIdx.x;     // 0..4095
  int cy = blockIdx.y, bb = blockIdx.z;
  float sa = part[(size_t)h*64 + bb*NCH + cy];
  float sb = part[(size_t)(HID + h)*64 + bb*NCH + cy];
  const unsigned char* pa = ab + ((size_t)(bb*TT + cy*CHUNK))*N1 + h;
  const unsigned char* pb = pa + HID;
  unsigned short* py = y + ((size_t)(bb*TT + cy*CHUNK))*HID + h;
  int t0 = cy*CHUNK;
  #pragma unroll 4
  for (int i = 0; i < CHUNK; ++i) {
    sa += e4m32f(pa[(size_t)i*N1]);
    sb += e4m32f(pb[(size_t)i*N1]);
    float inv = 1.0f / (float)(t0 + i + 1);
    py[(size_t)i*HID] = f2bf(sa*sb*inv*inv);
  }
}

// ---------- out = x + (1/64)*sum_z partial_z (fp16 partials) ----------
__global__ __launch_bounds__(256) void reduce_out(const unsigned short* __restrict__ p,
                                                  const float* __restrict__ x,
                                                  float* __restrict__ o) {
  size_t i = ((size_t)blockIdx.x*256 + threadIdx.x)*4;
  float4 xv = *(const float4*)(x + i);
  float s0 = 0.f, s1 = 0.f, s2 = 0.f, s3 = 0.f;
  #pragma unroll
  for (int z = 0; z < 4; ++z) {
    ushort4 u = *(const ushort4*)(p + (size_t)z*MROWS*EMB + i);
    s0 += h2f(u.x); s1 += h2f(u.y); s2 += h2f(u.z); s3 += h2f(u.w);
  }
  const float inv64 = 1.0f/64.0f;
  float4 ov; ov.x = xv.x + inv64*s0; ov.y = xv.y + inv64*s1;
             ov.z = xv.z + inv64*s2; ov.w = xv.w + inv64*s3;
  *(float4*)(o + i) = ov;
}

extern "C" void kernel_launch(void* const* d_in, const int* in_sizes, int n_in,
                              void* d_out, int out_size, void* d_ws, size_t ws_size,
                              hipStream_t stream) {
  const float* x  = (const float*)d_in[0];
  const float* W1 = (const float*)d_in[1];
  const float* W2 = (const float*)d_in[2];
  const float* W3 = (const float*)d_in[3];
  float* out = (float*)d_out;
  char* ws = (char*)d_ws;

  unsigned short* r_bf   = (unsigned short*)(ws);                 // 16 MiB
  unsigned short* w12_bf = (unsigned short*)(ws + 16777216ull);   // 16 MiB
  unsigned char*  w3_8   = (unsigned char*) (ws + 33554432ull);   // 4 MiB fp8 (x64)
  unsigned char*  ab8    = (unsigned char*) (ws + 37748736ull);   // 64 MiB fp8
  unsigned short* y_bf   = (unsigned short*)(ws + 104857600ull);  // 64 MiB
  unsigned char*  y8     = (unsigned char*) (ws + 171966464ull);  // 32 MiB fp8 (normalized)
  // psum (4 x 16 MiB fp16 GEMM2 partials) reuses dead ab8 (exactly 64 MiB)
  unsigned short* psum   = (unsigned short*)ab8;
  // part (per-chunk column sums) lives in d_out; dead before reduce_out
  float*          part   = (float*)d_out;                         // 2 MB

  conv_all<<<12288, 256, 0, stream>>>(W1, W2, W3, w12_bf, w3_8);
  rmsnorm_x<<<MROWS, 256, 0, stream>>>(x, r_bf);
  gemm_exp<<<1024, 512, 0, stream>>>(r_bf, w12_bf, ab8, part, EMB, N1);
  scan_prefix<<<64, 256, 0, stream>>>(part);
  scan_emit<<<dim3(16,NCH,2), 256, 0, stream>>>(ab8, part, y_bf);
  normq<<<MROWS, 256, 0, stream>>>(y_bf, y8);
  gemm_out<<<dim3(64,8,4), 256, 0, stream>>>(y8, w3_8, psum, HID, 1024, EMB);
  reduce_out<<<8192, 256, 0, stream>>>(psum, x, out);
}

// Round 3
// 373.905 us; speedup vs baseline: 1.0280x; 1.0237x over previous
//
#include <hip/hip_runtime.h>
#include <hip/hip_fp8.h>

#define EMB 1024
#define HID 4096
#define NB 2
#define TT 4096
#define MROWS (NB*TT)   // 8192
#define N1 (2*HID)      // 8192
#define CHUNK 128       // = GEMM1 row tile
#define NCH 32          // chunks per batch (TT/CHUNK)

typedef short short8 __attribute__((ext_vector_type(8)));
typedef float v4f   __attribute__((ext_vector_type(4)));

__device__ __forceinline__ unsigned short f2bf(float f) {
  unsigned int u = __float_as_uint(f);
  u += 0x7FFFu + ((u >> 16) & 1u);
  return (unsigned short)(u >> 16);
}
__device__ __forceinline__ float bf2f(unsigned short s) {
  return __uint_as_float(((unsigned int)s) << 16);
}
__device__ __forceinline__ unsigned char f2e4m3(float f) {
  __hip_fp8_e4m3 q(f);
  return *(unsigned char*)&q;
}
__device__ __forceinline__ float e4m32f(unsigned char c) {
  __hip_fp8_e4m3 q = *(__hip_fp8_e4m3*)&c;
  return (float)q;
}
__device__ __forceinline__ void g2l16(const void* g, void* l) {
  __builtin_amdgcn_global_load_lds(
      (const __attribute__((address_space(1))) void*)g,
      (__attribute__((address_space(3))) void*)l, 16, 0, 0);
}

__device__ __forceinline__ float block_reduce_sum(float v, float* sbuf) {
  #pragma unroll
  for (int off = 32; off; off >>= 1) v += __shfl_down(v, off, 64);
  int lane = threadIdx.x & 63, w = threadIdx.x >> 6;
  if (lane == 0) sbuf[w] = v;
  __syncthreads();
  return sbuf[0] + sbuf[1] + sbuf[2] + sbuf[3];
}

// ---------- merged weight convert: W1|W2 -> bf16, W3 -> fp8 x64 ----------
__global__ __launch_bounds__(256) void conv_all(const float* __restrict__ W1,
                                                const float* __restrict__ W2,
                                                const float* __restrict__ W3,
                                                unsigned short* __restrict__ o12,
                                                unsigned char* __restrict__ o3) {
  size_t i = ((size_t)blockIdx.x*256 + threadIdx.x)*4;
  if (i < 2ull*HID*EMB) {
    const float* s = (i < (size_t)HID*EMB) ? (W1 + i) : (W2 + (i - (size_t)HID*EMB));
    float4 v = *(const float4*)s;
    ushort4 u; u.x=f2bf(v.x); u.y=f2bf(v.y); u.z=f2bf(v.z); u.w=f2bf(v.w);
    *(ushort4*)(o12 + i) = u;
  } else {
    size_t off = i - 2ull*HID*EMB;
    float4 v = *(const float4*)(W3 + off);
    uchar4 u; u.x=f2e4m3(v.x*64.f); u.y=f2e4m3(v.y*64.f);
             u.z=f2e4m3(v.z*64.f); u.w=f2e4m3(v.w*64.f);
    *(uchar4*)(o3 + off) = u;
  }
}

// ---------- rmsnorm (fp32 in, bf16 out), row = EMB ----------
__global__ __launch_bounds__(256) void rmsnorm_x(const float* __restrict__ x,
                                                 unsigned short* __restrict__ r) {
  __shared__ float sbuf[4];
  int row = blockIdx.x;
  float4 v = *(const float4*)(x + (size_t)row*EMB + threadIdx.x*4);
  float ss = v.x*v.x + v.y*v.y + v.z*v.z + v.w*v.w;
  float tot = block_reduce_sum(ss, sbuf);
  float sc = rsqrtf(tot * (1.0f/EMB) + 1e-6f);
  ushort4 o; o.x=f2bf(v.x*sc); o.y=f2bf(v.y*sc); o.z=f2bf(v.z*sc); o.w=f2bf(v.w*sc);
  *(ushort4*)(r + (size_t)row*EMB + threadIdx.x*4) = o;
}

// ---------- normalize + quantize: y8 = fp8(y * rsqrt(mean(y^2)+eps)) ----------
__global__ __launch_bounds__(256) void normq(const unsigned short* __restrict__ y,
                                             unsigned char* __restrict__ y8) {
  __shared__ float sbuf[4];
  int row = blockIdx.x;
  const unsigned short* p = y + (size_t)row*HID + threadIdx.x*16;
  short8 v0 = *(const short8*)p;
  short8 v1 = *(const short8*)(p+8);
  float f[16]; float ss = 0.f;
  #pragma unroll
  for (int j=0;j<8;++j){ f[j]=bf2f((unsigned short)v0[j]); f[j+8]=bf2f((unsigned short)v1[j]); }
  #pragma unroll
  for (int j=0;j<16;++j) ss += f[j]*f[j];
  float tot = block_reduce_sum(ss, sbuf);
  float sc = rsqrtf(tot*(1.0f/HID) + 1e-6f);
  unsigned int w[4];
  #pragma unroll
  for (int g=0; g<4; ++g) {
    unsigned int a0 = f2e4m3(f[g*4+0]*sc);
    unsigned int a1 = f2e4m3(f[g*4+1]*sc);
    unsigned int a2 = f2e4m3(f[g*4+2]*sc);
    unsigned int a3 = f2e4m3(f[g*4+3]*sc);
    w[g] = a0 | (a1<<8) | (a2<<16) | (a3<<24);
  }
  uint4 o; o.x=w[0]; o.y=w[1]; o.z=w[2]; o.w=w[3];
  *(uint4*)(y8 + (size_t)row*HID + threadIdx.x*16) = o;
}

// ---------- GEMM1: C8 = (fp8 e4m3) exp(A*Bt^T); col-chunk sums -> part ----------
// bf16 MFMA, 128x128 tile, BK=64, XOR-swizzled LDS (32 KB).
// XCD-aware swizzle: 1D grid 4096; xcd = bid&7 owns col-stripe [xcd*8, xcd*8+8);
// within stripe, cols cycle fastest so the A row-tile is reused 8x while L2-hot.
// NOTE (R1/R2 post-mortem): 256^2 8-phase/counted-vmcnt restructures measured
// SLOWER here (161-167us vs 137us): 128KB LDS -> 1 block/CU kills the
// inter-block overlap this 3-blocks/CU structure gets for free (m114).
__global__ __launch_bounds__(256, 2)
void gemm_exp(const unsigned short* __restrict__ A,
              const unsigned short* __restrict__ Bt,
              unsigned char* __restrict__ C8,
              float* __restrict__ part,
              int K, int N) {
  __shared__ short lA[128*64];
  __shared__ short lB[128*64];
  const int tid  = threadIdx.x;
  const int lane = tid & 63;
  const int wm   = (tid >> 6) >> 1, wn = (tid >> 6) & 1;
  const int bid  = blockIdx.x;
  const int s0i  = bid >> 3;
  const int rowTile = s0i >> 3;                       // 0..63
  const int colTile = ((bid & 7) << 3) | (s0i & 7);   // 0..63
  const int rowBase = rowTile * 128;
  const int colBase = colTile * 128;

  v4f acc[4][4];
  #pragma unroll
  for (int i=0;i<4;++i)
    #pragma unroll
    for (int j=0;j<4;++j) acc[i][j] = (v4f){0.f,0.f,0.f,0.f};

  for (int k0 = 0; k0 < K; k0 += 64) {
    #pragma unroll
    for (int j = 0; j < 4; ++j) {
      int s = j*256 + tid;
      int m = s >> 3;
      int c = (s & 7) ^ (m & 7);
      g2l16(A + (size_t)(rowBase + m)*K + k0 + c*8, &lA[s*8]);
    }
    #pragma unroll
    for (int j = 0; j < 4; ++j) {
      int s = j*256 + tid;
      int m = s >> 3;
      int c = (s & 7) ^ (m & 7);
      g2l16(Bt + (size_t)(colBase + m)*K + k0 + c*8, &lB[s*8]);
    }
    __syncthreads();
    #pragma unroll
    for (int s2 = 0; s2 < 2; ++s2) {
      const int quad = lane >> 4;
      const int cc = s2*4 + quad;
      short8 aF[4], bF[4];
      #pragma unroll
      for (int mt = 0; mt < 4; ++mt) {
        int ml = wm*64 + mt*16 + (lane & 15);
        aF[mt] = *(const short8*)&lA[(ml*8 + (cc ^ (ml & 7)))*8];
      }
      #pragma unroll
      for (int nt = 0; nt < 4; ++nt) {
        int nl = wn*64 + nt*16 + (lane & 15);
        bF[nt] = *(const short8*)&lB[(nl*8 + (cc ^ (nl & 7)))*8];
      }
      #pragma unroll
      for (int mt = 0; mt < 4; ++mt)
        #pragma unroll
        for (int nt = 0; nt < 4; ++nt)
          acc[mt][nt] = __builtin_amdgcn_mfma_f32_16x16x32_bf16(aF[mt], bF[nt], acc[mt][nt], 0, 0, 0);
    }
    __syncthreads();
  }

  const int quad = lane >> 4, c15 = lane & 15;
  float csum[4] = {0.f, 0.f, 0.f, 0.f};
  #pragma unroll
  for (int mt = 0; mt < 4; ++mt) {
    #pragma unroll
    for (int nt = 0; nt < 4; ++nt) {
      int col = colBase + wn*64 + nt*16 + c15;
      #pragma unroll
      for (int r = 0; r < 4; ++r) {
        int row = rowBase + wm*64 + mt*16 + quad*4 + r;
        size_t idx = (size_t)row*N + col;
        float e = __expf(acc[mt][nt][r]);
        C8[idx] = f2e4m3(e);
        csum[nt] += e;
      }
    }
  }
  float* cs = (float*)lA;   // [2][128], reuses dead lA
  #pragma unroll
  for (int nt = 0; nt < 4; ++nt) {
    float s = csum[nt];
    s += __shfl_xor(s, 16, 64);
    s += __shfl_xor(s, 32, 64);
    if (lane < 16) cs[wm*128 + wn*64 + nt*16 + lane] = s;
  }
  __syncthreads();
  if (tid < 128)
    part[(size_t)(colBase + tid)*64 + rowTile] = cs[tid] + cs[128 + tid];
}

// ---------- GEMM2 (fp8): out = x + (1/64) * yhat8 * (w3*64)^T ----------
// 128x128 tile, BK=128 fp8, full K (no split-K), x-add fused into epilogue.
// Replaces the old split-K(4) + fp16 psum + reduce_out: saves ~160 MB of
// HBM round-trip (64W + 64R psum + extra x/out pass) and one kernel launch.
// Grid (row=64, col=8) = 512 blocks = 2/CU; B-panel (4 MB) is L2-resident.
__global__ __launch_bounds__(256, 2)
void gemm_out(const unsigned char* __restrict__ A8,
              const unsigned char* __restrict__ B8,
              const float* __restrict__ x,
              float* __restrict__ out,
              int K, int N) {
  __shared__ unsigned char lA8[128*128];
  __shared__ unsigned char lB8[128*128];
  const int tid  = threadIdx.x;
  const int lane = tid & 63;
  const int wm   = (tid >> 6) >> 1, wn = (tid >> 6) & 1;
  const int rowBase = blockIdx.x * 128;
  const int colBase = blockIdx.y * 128;

  v4f acc[4][4];
  #pragma unroll
  for (int i=0;i<4;++i)
    #pragma unroll
    for (int j=0;j<4;++j) acc[i][j] = (v4f){0.f,0.f,0.f,0.f};

  for (int k0 = 0; k0 < K; k0 += 128) {
    #pragma unroll
    for (int j = 0; j < 4; ++j) {
      int s = j*256 + tid;
      int m = s >> 3;
      int c = (s & 7) ^ (m & 7);
      g2l16(A8 + (size_t)(rowBase + m)*K + k0 + c*16, &lA8[s*16]);
    }
    #pragma unroll
    for (int j = 0; j < 4; ++j) {
      int s = j*256 + tid;
      int m = s >> 3;
      int c = (s & 7) ^ (m & 7);
      g2l16(B8 + (size_t)(colBase + m)*K + k0 + c*16, &lB8[s*16]);
    }
    __syncthreads();
    #pragma unroll
    for (int s2 = 0; s2 < 4; ++s2) {
      const int quad = lane >> 4;
      const int cc = s2*2 + (quad >> 1);   // logical 16B chunk
      const int hh = quad & 1;             // 8B half within chunk
      long aF[4], bF[4];
      #pragma unroll
      for (int mt = 0; mt < 4; ++mt) {
        int ml = wm*64 + mt*16 + (lane & 15);
        aF[mt] = *(const long*)&lA8[ml*128 + ((cc ^ (ml & 7))<<4) + (hh<<3)];
      }
      #pragma unroll
      for (int nt = 0; nt < 4; ++nt) {
        int nl = wn*64 + nt*16 + (lane & 15);
        bF[nt] = *(const long*)&lB8[nl*128 + ((cc ^ (nl & 7))<<4) + (hh<<3)];
      }
      #pragma unroll
      for (int mt = 0; mt < 4; ++mt)
        #pragma unroll
        for (int nt = 0; nt < 4; ++nt)
          acc[mt][nt] = __builtin_amdgcn_mfma_f32_16x16x32_fp8_fp8(aF[mt], bF[nt], acc[mt][nt], 0, 0, 0);
    }
    __syncthreads();
  }

  const int quad = lane >> 4, c15 = lane & 15;
  const float inv64 = 1.0f/64.0f;
  #pragma unroll
  for (int mt = 0; mt < 4; ++mt) {
    #pragma unroll
    for (int nt = 0; nt < 4; ++nt) {
      int col = colBase + wn*64 + nt*16 + c15;
      #pragma unroll
      for (int r = 0; r < 4; ++r) {
        int row = rowBase + wm*64 + mt*16 + quad*4 + r;
        size_t idx = (size_t)row*N + col;
        out[idx] = x[idx] + inv64*acc[mt][nt][r];
      }
    }
  }
}

// ---------- exclusive prefix over 32 chunks per (col, batch) ----------
__global__ __launch_bounds__(256) void scan_prefix(float* __restrict__ part) {
  int idx = blockIdx.x*256 + threadIdx.x;   // 0..16383
  int col = idx >> 1, bb = idx & 1;
  float* p = part + (size_t)col*64 + bb*NCH;
  float run = 0.f;
  #pragma unroll
  for (int c = 0; c < NCH; ++c) { float v = p[c]; p[c] = run; run += v; }
}

// ---------- emit y = Sa*Sb/t^2 (bf16) from fp8 exp values ----------
__global__ __launch_bounds__(256) void scan_emit(const unsigned char* __restrict__ ab,
                                                 const float* __restrict__ part,
                                                 unsigned short* __restrict__ y) {
  int h = blockIdx.x*256 + threadIdx.x;     // 0..4095
  int cy = blockIdx.y, bb = blockIdx.z;
  float sa = part[(size_t)h*64 + bb*NCH + cy];
  float sb = part[(size_t)(HID + h)*64 + bb*NCH + cy];
  const unsigned char* pa = ab + ((size_t)(bb*TT + cy*CHUNK))*N1 + h;
  const unsigned char* pb = pa + HID;
  unsigned short* py = y + ((size_t)(bb*TT + cy*CHUNK))*HID + h;
  int t0 = cy*CHUNK;
  #pragma unroll 4
  for (int i = 0; i < CHUNK; ++i) {
    sa += e4m32f(pa[(size_t)i*N1]);
    sb += e4m32f(pb[(size_t)i*N1]);
    float inv = 1.0f / (float)(t0 + i + 1);
    py[(size_t)i*HID] = f2bf(sa*sb*inv*inv);
  }
}

extern "C" void kernel_launch(void* const* d_in, const int* in_sizes, int n_in,
                              void* d_out, int out_size, void* d_ws, size_t ws_size,
                              hipStream_t stream) {
  const float* x  = (const float*)d_in[0];
  const float* W1 = (const float*)d_in[1];
  const float* W2 = (const float*)d_in[2];
  const float* W3 = (const float*)d_in[3];
  float* out = (float*)d_out;
  char* ws = (char*)d_ws;

  unsigned short* r_bf   = (unsigned short*)(ws);                 // 16 MiB
  unsigned short* w12_bf = (unsigned short*)(ws + 16777216ull);   // 16 MiB
  unsigned char*  w3_8   = (unsigned char*) (ws + 33554432ull);   // 4 MiB fp8 (x64)
  unsigned char*  ab8    = (unsigned char*) (ws + 37748736ull);   // 64 MiB fp8
  unsigned short* y_bf   = (unsigned short*)(ws + 104857600ull);  // 64 MiB
  unsigned char*  y8     = (unsigned char*) (ws + 171966464ull);  // 32 MiB fp8 (normalized)
  // part (per-chunk column sums) lives in d_out; dead before gemm_out
  float*          part   = (float*)d_out;                         // 2 MB

  conv_all<<<12288, 256, 0, stream>>>(W1, W2, W3, w12_bf, w3_8);
  rmsnorm_x<<<MROWS, 256, 0, stream>>>(x, r_bf);
  gemm_exp<<<4096, 256, 0, stream>>>(r_bf, w12_bf, ab8, part, EMB, N1);
  scan_prefix<<<64, 256, 0, stream>>>(part);
  scan_emit<<<dim3(16,NCH,2), 256, 0, stream>>>(ab8, part, y_bf);
  normq<<<MROWS, 256, 0, stream>>>(y_bf, y8);
  gemm_out<<<dim3(64,8), 256, 0, stream>>>(y8, w3_8, x, out, HID, EMB);
}

// Round 4
// 353.738 us; speedup vs baseline: 1.0866x; 1.0570x over previous
//
#include <hip/hip_runtime.h>
#include <hip/hip_fp8.h>

#define EMB 1024
#define HID 4096
#define NB 2
#define TT 4096
#define MROWS (NB*TT)   // 8192
#define N1 (2*HID)      // 8192
#define CHUNK 128       // = GEMM1 row tile
#define NCH 32          // chunks per batch (TT/CHUNK)

typedef short short8 __attribute__((ext_vector_type(8)));
typedef float v4f   __attribute__((ext_vector_type(4)));
typedef int   v4i   __attribute__((ext_vector_type(4)));
typedef int   v8i   __attribute__((ext_vector_type(8)));

__device__ __forceinline__ unsigned short f2bf(float f) {
  unsigned int u = __float_as_uint(f);
  u += 0x7FFFu + ((u >> 16) & 1u);
  return (unsigned short)(u >> 16);
}
__device__ __forceinline__ float bf2f(unsigned short s) {
  return __uint_as_float(((unsigned int)s) << 16);
}
__device__ __forceinline__ unsigned char f2e4m3(float f) {
  __hip_fp8_e4m3 q(f);
  return *(unsigned char*)&q;
}
__device__ __forceinline__ float e4m32f(unsigned char c) {
  __hip_fp8_e4m3 q = *(__hip_fp8_e4m3*)&c;
  return (float)q;
}
__device__ __forceinline__ void g2l16(const void* g, void* l) {
  __builtin_amdgcn_global_load_lds(
      (const __attribute__((address_space(1))) void*)g,
      (__attribute__((address_space(3))) void*)l, 16, 0, 0);
}

__device__ __forceinline__ float block_reduce_sum(float v, float* sbuf) {
  #pragma unroll
  for (int off = 32; off; off >>= 1) v += __shfl_down(v, off, 64);
  int lane = threadIdx.x & 63, w = threadIdx.x >> 6;
  if (lane == 0) sbuf[w] = v;
  __syncthreads();
  return sbuf[0] + sbuf[1] + sbuf[2] + sbuf[3];
}

// ---------- merged weight convert: W1|W2 -> bf16, W3 -> fp8 x64 ----------
__global__ __launch_bounds__(256) void conv_all(const float* __restrict__ W1,
                                                const float* __restrict__ W2,
                                                const float* __restrict__ W3,
                                                unsigned short* __restrict__ o12,
                                                unsigned char* __restrict__ o3) {
  size_t i = ((size_t)blockIdx.x*256 + threadIdx.x)*4;
  if (i < 2ull*HID*EMB) {
    const float* s = (i < (size_t)HID*EMB) ? (W1 + i) : (W2 + (i - (size_t)HID*EMB));
    float4 v = *(const float4*)s;
    ushort4 u; u.x=f2bf(v.x); u.y=f2bf(v.y); u.z=f2bf(v.z); u.w=f2bf(v.w);
    *(ushort4*)(o12 + i) = u;
  } else {
    size_t off = i - 2ull*HID*EMB;
    float4 v = *(const float4*)(W3 + off);
    uchar4 u; u.x=f2e4m3(v.x*64.f); u.y=f2e4m3(v.y*64.f);
             u.z=f2e4m3(v.z*64.f); u.w=f2e4m3(v.w*64.f);
    *(uchar4*)(o3 + off) = u;
  }
}

// ---------- rmsnorm (fp32 in, bf16 out), row = EMB ----------
__global__ __launch_bounds__(256) void rmsnorm_x(const float* __restrict__ x,
                                                 unsigned short* __restrict__ r) {
  __shared__ float sbuf[4];
  int row = blockIdx.x;
  float4 v = *(const float4*)(x + (size_t)row*EMB + threadIdx.x*4);
  float ss = v.x*v.x + v.y*v.y + v.z*v.z + v.w*v.w;
  float tot = block_reduce_sum(ss, sbuf);
  float sc = rsqrtf(tot * (1.0f/EMB) + 1e-6f);
  ushort4 o; o.x=f2bf(v.x*sc); o.y=f2bf(v.y*sc); o.z=f2bf(v.z*sc); o.w=f2bf(v.w*sc);
  *(ushort4*)(r + (size_t)row*EMB + threadIdx.x*4) = o;
}

// ---------- normalize + quantize: y8 = fp8(y * rsqrt(mean(y^2)+eps)) ----------
__global__ __launch_bounds__(256) void normq(const unsigned short* __restrict__ y,
                                             unsigned char* __restrict__ y8) {
  __shared__ float sbuf[4];
  int row = blockIdx.x;
  const unsigned short* p = y + (size_t)row*HID + threadIdx.x*16;
  short8 v0 = *(const short8*)p;
  short8 v1 = *(const short8*)(p+8);
  float f[16]; float ss = 0.f;
  #pragma unroll
  for (int j=0;j<8;++j){ f[j]=bf2f((unsigned short)v0[j]); f[j+8]=bf2f((unsigned short)v1[j]); }
  #pragma unroll
  for (int j=0;j<16;++j) ss += f[j]*f[j];
  float tot = block_reduce_sum(ss, sbuf);
  float sc = rsqrtf(tot*(1.0f/HID) + 1e-6f);
  unsigned int w[4];
  #pragma unroll
  for (int g=0; g<4; ++g) {
    unsigned int a0 = f2e4m3(f[g*4+0]*sc);
    unsigned int a1 = f2e4m3(f[g*4+1]*sc);
    unsigned int a2 = f2e4m3(f[g*4+2]*sc);
    unsigned int a3 = f2e4m3(f[g*4+3]*sc);
    w[g] = a0 | (a1<<8) | (a2<<16) | (a3<<24);
  }
  uint4 o; o.x=w[0]; o.y=w[1]; o.z=w[2]; o.w=w[3];
  *(uint4*)(y8 + (size_t)row*HID + threadIdx.x*16) = o;
}

// ---------- GEMM1: C8 = (fp8 e4m3) exp(A*Bt^T); col-chunk sums -> part ----------
// bf16 MFMA, 128x128 tile, BK=64, XOR-swizzled LDS (32 KB).
// XCD-aware swizzle: 1D grid 4096; xcd = bid&7 owns col-stripe [xcd*8, xcd*8+8);
// within stripe, cols cycle fastest so the A row-tile is reused 8x while L2-hot.
// NOTE (R1/R2 post-mortem): 256^2 8-phase/counted-vmcnt restructures measured
// SLOWER here (161-167us vs 137us): 128KB LDS -> 1 block/CU kills the
// inter-block overlap this 3-blocks/CU structure gets for free (m114).
__global__ __launch_bounds__(256, 2)
void gemm_exp(const unsigned short* __restrict__ A,
              const unsigned short* __restrict__ Bt,
              unsigned char* __restrict__ C8,
              float* __restrict__ part,
              int K, int N) {
  __shared__ short lA[128*64];
  __shared__ short lB[128*64];
  const int tid  = threadIdx.x;
  const int lane = tid & 63;
  const int wm   = (tid >> 6) >> 1, wn = (tid >> 6) & 1;
  const int bid  = blockIdx.x;
  const int s0i  = bid >> 3;
  const int rowTile = s0i >> 3;                       // 0..63
  const int colTile = ((bid & 7) << 3) | (s0i & 7);   // 0..63
  const int rowBase = rowTile * 128;
  const int colBase = colTile * 128;

  v4f acc[4][4];
  #pragma unroll
  for (int i=0;i<4;++i)
    #pragma unroll
    for (int j=0;j<4;++j) acc[i][j] = (v4f){0.f,0.f,0.f,0.f};

  for (int k0 = 0; k0 < K; k0 += 64) {
    #pragma unroll
    for (int j = 0; j < 4; ++j) {
      int s = j*256 + tid;
      int m = s >> 3;
      int c = (s & 7) ^ (m & 7);
      g2l16(A + (size_t)(rowBase + m)*K + k0 + c*8, &lA[s*8]);
    }
    #pragma unroll
    for (int j = 0; j < 4; ++j) {
      int s = j*256 + tid;
      int m = s >> 3;
      int c = (s & 7) ^ (m & 7);
      g2l16(Bt + (size_t)(colBase + m)*K + k0 + c*8, &lB[s*8]);
    }
    __syncthreads();
    #pragma unroll
    for (int s2 = 0; s2 < 2; ++s2) {
      const int quad = lane >> 4;
      const int cc = s2*4 + quad;
      short8 aF[4], bF[4];
      #pragma unroll
      for (int mt = 0; mt < 4; ++mt) {
        int ml = wm*64 + mt*16 + (lane & 15);
        aF[mt] = *(const short8*)&lA[(ml*8 + (cc ^ (ml & 7)))*8];
      }
      #pragma unroll
      for (int nt = 0; nt < 4; ++nt) {
        int nl = wn*64 + nt*16 + (lane & 15);
        bF[nt] = *(const short8*)&lB[(nl*8 + (cc ^ (nl & 7)))*8];
      }
      #pragma unroll
      for (int mt = 0; mt < 4; ++mt)
        #pragma unroll
        for (int nt = 0; nt < 4; ++nt)
          acc[mt][nt] = __builtin_amdgcn_mfma_f32_16x16x32_bf16(aF[mt], bF[nt], acc[mt][nt], 0, 0, 0);
    }
    __syncthreads();
  }

  const int quad = lane >> 4, c15 = lane & 15;
  float csum[4] = {0.f, 0.f, 0.f, 0.f};
  #pragma unroll
  for (int mt = 0; mt < 4; ++mt) {
    #pragma unroll
    for (int nt = 0; nt < 4; ++nt) {
      int col = colBase + wn*64 + nt*16 + c15;
      #pragma unroll
      for (int r = 0; r < 4; ++r) {
        int row = rowBase + wm*64 + mt*16 + quad*4 + r;
        size_t idx = (size_t)row*N + col;
        float e = __expf(acc[mt][nt][r]);
        C8[idx] = f2e4m3(e);
        csum[nt] += e;
      }
    }
  }
  float* cs = (float*)lA;   // [2][128], reuses dead lA
  #pragma unroll
  for (int nt = 0; nt < 4; ++nt) {
    float s = csum[nt];
    s += __shfl_xor(s, 16, 64);
    s += __shfl_xor(s, 32, 64);
    if (lane < 16) cs[wm*128 + wn*64 + nt*16 + lane] = s;
  }
  __syncthreads();
  if (tid < 128)
    part[(size_t)(colBase + tid)*64 + rowTile] = cs[tid] + cs[128 + tid];
}

// ---------- GEMM2 (fp8, MX-unit-scale): out = x + (1/64)*yhat8*(w3*64)^T ----
// 128x128 tile, BK=128 fp8. Uses mfma_scale_f32_16x16x128_f8f6f4 with
// E8M0 unit scales (0x7F): bit-identical math to plain fp8 MFMA but at the
// MX rate (~4.7 PF vs ~2.1 PF for non-scaled fp8 -> 16 MFMA/tile vs 64).
// Fragment: lane holds row (lane&15), k-block (lane>>4) of 32 consecutive
// fp8 = two swizzled 16B LDS chunks (2q)^s and (2q+1)^s, s = row&7.
// Bank math: each 128B row = one full 32-bank sweep -> accesses stay at the
// 8/bank minimum for b128; conflict counter stays 0.
// Grid (row=64, col=8) = 512 blocks = 2/CU; B-panel (4 MB) is L2-resident.
__global__ __launch_bounds__(256, 2)
void gemm_out(const unsigned char* __restrict__ A8,
              const unsigned char* __restrict__ B8,
              const float* __restrict__ x,
              float* __restrict__ out,
              int K, int N) {
  __shared__ unsigned char lA8[128*128];
  __shared__ unsigned char lB8[128*128];
  const int tid  = threadIdx.x;
  const int lane = tid & 63;
  const int wm   = (tid >> 6) >> 1, wn = (tid >> 6) & 1;
  const int rowBase = blockIdx.x * 128;
  const int colBase = blockIdx.y * 128;
  const int q   = lane >> 4;     // k-block 0..3 (32 fp8 each)
  const int r15 = lane & 15;

  v4f acc[4][4];
  #pragma unroll
  for (int i=0;i<4;++i)
    #pragma unroll
    for (int j=0;j<4;++j) acc[i][j] = (v4f){0.f,0.f,0.f,0.f};

  for (int k0 = 0; k0 < K; k0 += 128) {
    #pragma unroll
    for (int j = 0; j < 4; ++j) {
      int s = j*256 + tid;
      int m = s >> 3;
      int c = (s & 7) ^ (m & 7);
      g2l16(A8 + (size_t)(rowBase + m)*K + k0 + c*16, &lA8[s*16]);
    }
    #pragma unroll
    for (int j = 0; j < 4; ++j) {
      int s = j*256 + tid;
      int m = s >> 3;
      int c = (s & 7) ^ (m & 7);
      g2l16(B8 + (size_t)(colBase + m)*K + k0 + c*16, &lB8[s*16]);
    }
    __syncthreads();
    v8i aF[4], bF[4];
    #pragma unroll
    for (int mt = 0; mt < 4; ++mt) {
      int ml = wm*64 + mt*16 + r15;
      int s  = ml & 7;
      v4i lo = *(const v4i*)&lA8[ml*128 + (((2*q)   ^ s)<<4)];
      v4i hi = *(const v4i*)&lA8[ml*128 + (((2*q+1) ^ s)<<4)];
      aF[mt] = __builtin_shufflevector(lo, hi, 0,1,2,3,4,5,6,7);
    }
    #pragma unroll
    for (int nt = 0; nt < 4; ++nt) {
      int nl = wn*64 + nt*16 + r15;
      int s  = nl & 7;
      v4i lo = *(const v4i*)&lB8[nl*128 + (((2*q)   ^ s)<<4)];
      v4i hi = *(const v4i*)&lB8[nl*128 + (((2*q+1) ^ s)<<4)];
      bF[nt] = __builtin_shufflevector(lo, hi, 0,1,2,3,4,5,6,7);
    }
    #pragma unroll
    for (int mt = 0; mt < 4; ++mt)
      #pragma unroll
      for (int nt = 0; nt < 4; ++nt)
        acc[mt][nt] = __builtin_amdgcn_mfma_scale_f32_16x16x128_f8f6f4(
            aF[mt], bF[nt], acc[mt][nt],
            0, 0,                      // cbsz=fp8(e4m3), blgp=fp8(e4m3)
            0, 0x7F7F7F7F,             // opsel_a, scale_a = E8M0 1.0
            0, 0x7F7F7F7F);            // opsel_b, scale_b = E8M0 1.0
    __syncthreads();
  }

  const int quad = lane >> 4, c15 = lane & 15;
  const float inv64 = 1.0f/64.0f;
  #pragma unroll
  for (int mt = 0; mt < 4; ++mt) {
    #pragma unroll
    for (int nt = 0; nt < 4; ++nt) {
      int col = colBase + wn*64 + nt*16 + c15;
      #pragma unroll
      for (int r = 0; r < 4; ++r) {
        int row = rowBase + wm*64 + mt*16 + quad*4 + r;
        size_t idx = (size_t)row*N + col;
        out[idx] = x[idx] + inv64*acc[mt][nt][r];
      }
    }
  }
}

// ---------- exclusive prefix over 32 chunks per (col, batch) ----------
__global__ __launch_bounds__(256) void scan_prefix(float* __restrict__ part) {
  int idx = blockIdx.x*256 + threadIdx.x;   // 0..16383
  int col = idx >> 1, bb = idx & 1;
  float* p = part + (size_t)col*64 + bb*NCH;
  float run = 0.f;
  #pragma unroll
  for (int c = 0; c < NCH; ++c) { float v = p[c]; p[c] = run; run += v; }
}

// ---------- emit y = Sa*Sb/t^2 (bf16) from fp8 exp values ----------
__global__ __launch_bounds__(256) void scan_emit(const unsigned char* __restrict__ ab,
                                                 const float* __restrict__ part,
                                                 unsigned short* __restrict__ y) {
  int h = blockIdx.x*256 + threadIdx.x;     // 0..4095
  int cy = blockIdx.y, bb = blockIdx.z;
  float sa = part[(size_t)h*64 + bb*NCH + cy];
  float sb = part[(size_t)(HID + h)*64 + bb*NCH + cy];
  const unsigned char* pa = ab + ((size_t)(bb*TT + cy*CHUNK))*N1 + h;
  const unsigned char* pb = pa + HID;
  unsigned short* py = y + ((size_t)(bb*TT + cy*CHUNK))*HID + h;
  int t0 = cy*CHUNK;
  #pragma unroll 4
  for (int i = 0; i < CHUNK; ++i) {
    sa += e4m32f(pa[(size_t)i*N1]);
    sb += e4m32f(pb[(size_t)i*N1]);
    float inv = 1.0f / (float)(t0 + i + 1);
    py[(size_t)i*HID] = f2bf(sa*sb*inv*inv);
  }
}

extern "C" void kernel_launch(void* const* d_in, const int* in_sizes, int n_in,
                              void* d_out, int out_size, void* d_ws, size_t ws_size,
                              hipStream_t stream) {
  const float* x  = (const float*)d_in[0];
  const float* W1 = (const float*)d_in[1];
  const float* W2 = (const float*)d_in[2];
  const float* W3 = (const float*)d_in[3];
  float* out = (float*)d_out;
  char* ws = (char*)d_ws;

  unsigned short* r_bf   = (unsigned short*)(ws);                 // 16 MiB
  unsigned short* w12_bf = (unsigned short*)(ws + 16777216ull);   // 16 MiB
  unsigned char*  w3_8   = (unsigned char*) (ws + 33554432ull);   // 4 MiB fp8 (x64)
  unsigned char*  ab8    = (unsigned char*) (ws + 37748736ull);   // 64 MiB fp8
  unsigned short* y_bf   = (unsigned short*)(ws + 104857600ull);  // 64 MiB
  unsigned char*  y8     = (unsigned char*) (ws + 171966464ull);  // 32 MiB fp8 (normalized)
  // part (per-chunk column sums) lives in d_out; dead before gemm_out
  float*          part   = (float*)d_out;                         // 2 MB

  conv_all<<<12288, 256, 0, stream>>>(W1, W2, W3, w12_bf, w3_8);
  rmsnorm_x<<<MROWS, 256, 0, stream>>>(x, r_bf);
  gemm_exp<<<4096, 256, 0, stream>>>(r_bf, w12_bf, ab8, part, EMB, N1);
  scan_prefix<<<64, 256, 0, stream>>>(part);
  scan_emit<<<dim3(16,NCH,2), 256, 0, stream>>>(ab8, part, y_bf);
  normq<<<MROWS, 256, 0, stream>>>(y_bf, y8);
  gemm_out<<<dim3(64,8), 256, 0, stream>>>(y8, w3_8, x, out, HID, EMB);
}